// Round 2
// baseline (427.899 us; speedup 1.0000x reference)
//
#include <hip/hip_runtime.h>
#include <hip/hip_bf16.h>

// GCN: 2x (GCNConv -> ReLU -> BatchNorm) -> Linear
// B=2, N=20000, E=640000, H=IN=128, OUT=10
//
// Round-5 structure (8 dispatches):
//  - ELL adjacency in ONE scatter pass (atomic cursor == degree counter)
//  - h pre-scaled by dinv at GEMM epilogue: agg is a pure unweighted sum
//    (norm = dinv[s]*dinv[d]  =>  out = dinv[d] * sum(dinv[s]*h[s]))
//  - agg: 1 wave = 1 node, 2 edges per uint4 load instruction
//    (lane l -> chunk l&31 of edge j+(l>>5); 16B/lane loads, 16 edges in
//    flight, no intra-wave divergence; half-wave sums combined via shfl_xor(32))
//  - BN stats FUSED into agg epilogue (shfl+LDS reduce -> 256 atomicAdds/blk)
//  - BN affine computed per-block in consumers (gemm2: a,c + d=c@W2 init;
//    gemmout: a,c in-register) -- no single-workgroup finalize kernels

constexpr int Nn   = 20000;
constexpr int Ee   = 640000;
constexpr int OUTd = 10;
constexpr int Mm   = 2 * Nn;   // 40000 rows
constexpr int ELLW = 96;       // max degree slots; Poisson(32) => P(overflow) ~ 1e-14
#define EPSV 1e-5f
constexpr float INV_M = 1.0f / (float)Mm;

using frag16 = __attribute__((ext_vector_type(8))) short;  // 8 bf16
using f32x4  = __attribute__((ext_vector_type(4))) float;

__device__ inline short bf(float f) {
    union { __hip_bfloat16 h; short s; } u;
    u.h = __float2bfloat16(f);
    return u.s;
}
__device__ inline float lo16(unsigned u) { union { unsigned v; float f; } x; x.v = u << 16;        return x.f; }
__device__ inline float hi16(unsigned u) { union { unsigned v; float f; } x; x.v = u & 0xffff0000u; return x.f; }
__device__ inline unsigned pack2(float f0, float f1) {
    return (unsigned)(unsigned short)bf(f0) | ((unsigned)(unsigned short)bf(f1) << 16);
}

// ---------------- adjacency: one-pass ELL scatter ----------------
__global__ __launch_bounds__(256) void scatter_ell_k(const int* __restrict__ src, const int* __restrict__ dst,
                                                     int* __restrict__ cnt, int* __restrict__ ell) {
    int e = blockIdx.x * 256 + threadIdx.x;
    if (e < Ee) {
        int d = dst[e];
        int pos = atomicAdd(&cnt[d], 1);
        if (pos < ELLW) ell[(size_t)d * ELLW + pos] = src[e];
    }
}

__global__ __launch_bounds__(256) void dinv_k(const int* __restrict__ cnt, float* __restrict__ dinv) {
    int n = blockIdx.x * 256 + threadIdx.x;
    if (n < Nn) dinv[n] = rsqrtf((float)cnt[n] + 1.0f);  // +1 self-loop
}

// ---------------- GEMM1: (40000 x 128 fp32) @ (128 x 128) -> dinv-scaled bf16 interleaved ----------------
__global__ __launch_bounds__(256) void gemm1_k(const float* __restrict__ A,
                                               const float* __restrict__ W,
                                               const float* __restrict__ dinv,
                                               unsigned short* __restrict__ Hout) {
    __shared__ short Wl[128 * 136];  // Wl[n*136 + k] bf16; stride 272B -> free 2-way
    int t = threadIdx.x;

    for (int it = 0; it < 8; ++it) {
        int lin = it * 256 + t;
        int kp  = lin & 63;
        int n4  = (lin >> 6) * 4;
        float4 w0 = *(const float4*)(W + (size_t)(2 * kp) * 128 + n4);
        float4 w1 = *(const float4*)(W + (size_t)(2 * kp + 1) * 128 + n4);
        *(unsigned*)&Wl[(n4 + 0) * 136 + 2 * kp] = pack2(w0.x, w1.x);
        *(unsigned*)&Wl[(n4 + 1) * 136 + 2 * kp] = pack2(w0.y, w1.y);
        *(unsigned*)&Wl[(n4 + 2) * 136 + 2 * kp] = pack2(w0.z, w1.z);
        *(unsigned*)&Wl[(n4 + 3) * 136 + 2 * kp] = pack2(w0.w, w1.w);
    }
    __syncthreads();

    int wv = t >> 6, l = t & 63;
    int row_q = l >> 4, lane16 = l & 15;
    int row0 = blockIdx.x * 64 + wv * 16;

    frag16 a[4];
    const float* Arow = A + (size_t)(row0 + lane16) * 128;
    #pragma unroll
    for (int q = 0; q < 4; ++q) {
        int k0 = q * 32 + row_q * 8;
        float4 v0 = *(const float4*)(Arow + k0);
        float4 v1 = *(const float4*)(Arow + k0 + 4);
        frag16 fa = { bf(v0.x), bf(v0.y), bf(v0.z), bf(v0.w),
                      bf(v1.x), bf(v1.y), bf(v1.z), bf(v1.w) };
        a[q] = fa;
    }

    f32x4 acc[8];
    #pragma unroll
    for (int c = 0; c < 8; ++c) acc[c] = (f32x4){0.f, 0.f, 0.f, 0.f};

    #pragma unroll
    for (int c = 0; c < 8; ++c) {
        int n = c * 16 + lane16;
        #pragma unroll
        for (int q = 0; q < 4; ++q) {
            int k0 = q * 32 + row_q * 8;
            frag16 b = *(const frag16*)&Wl[n * 136 + k0];
            acc[c] = __builtin_amdgcn_mfma_f32_16x16x32_bf16(a[q], b, acc[c], 0, 0, 0);
        }
    }

    #pragma unroll
    for (int r = 0; r < 4; ++r) {
        int rg = row0 + row_q * 4 + r;
        int b  = rg >= Nn;
        int n  = rg - b * Nn;
        float dv = dinv[n];
        unsigned short* dst = Hout + (size_t)n * 256 + b * 128;
        #pragma unroll
        for (int c = 0; c < 8; ++c)
            dst[c * 16 + lane16] = (unsigned short)bf(acc[c][r] * dv);
    }
}

// ---------------- GEMM2: (bf16 act) @ (diag(a1)*W2) + c1@W2 -> dinv-scaled bf16 ----------------
__global__ __launch_bounds__(256) void gemm2_k(const unsigned short* __restrict__ Abf,
                                               const float* __restrict__ W,
                                               const float* __restrict__ g,
                                               const float* __restrict__ bt,
                                               const float* __restrict__ S,
                                               const float* __restrict__ dinv,
                                               unsigned short* __restrict__ Hout) {
    __shared__ short Wl[128 * 136];
    __shared__ float al[128], cl[128], dpart[2][128];
    int t = threadIdx.x;

    if (t < 128) {
        float s  = S[t];
        float ss = S[128 + t];
        float m   = s * INV_M;
        float var = ss * INV_M - m * m;
        float a   = g[t] * rsqrtf(var + EPSV);
        float c   = bt[t] - m * a;
        al[t] = a; cl[t] = c;
    }
    __syncthreads();

    // stage W scaled by a (rows k scaled by a[k])
    for (int it = 0; it < 8; ++it) {
        int lin = it * 256 + t;
        int kp  = lin & 63;
        int n4  = (lin >> 6) * 4;
        float a0 = al[2 * kp], a1 = al[2 * kp + 1];
        float4 w0 = *(const float4*)(W + (size_t)(2 * kp) * 128 + n4);
        float4 w1 = *(const float4*)(W + (size_t)(2 * kp + 1) * 128 + n4);
        w0.x *= a0; w0.y *= a0; w0.z *= a0; w0.w *= a0;
        w1.x *= a1; w1.y *= a1; w1.z *= a1; w1.w *= a1;
        *(unsigned*)&Wl[(n4 + 0) * 136 + 2 * kp] = pack2(w0.x, w1.x);
        *(unsigned*)&Wl[(n4 + 1) * 136 + 2 * kp] = pack2(w0.y, w1.y);
        *(unsigned*)&Wl[(n4 + 2) * 136 + 2 * kp] = pack2(w0.z, w1.z);
        *(unsigned*)&Wl[(n4 + 3) * 136 + 2 * kp] = pack2(w0.w, w1.w);
    }

    // d[col] = sum_k c[k] * W[k][col], split over two half-K per thread
    {
        int col = t & 127, hh = t >> 7;
        const float* Wc0 = W + (size_t)(hh * 64) * 128 + col;
        float dp = 0.f;
        #pragma unroll 8
        for (int k = 0; k < 64; ++k) dp += cl[hh * 64 + k] * Wc0[(size_t)k * 128];
        dpart[hh][col] = dp;
    }
    __syncthreads();

    int wv = t >> 6, l = t & 63;
    int row_q = l >> 4, lane16 = l & 15;
    int row0 = blockIdx.x * 64 + wv * 16;

    int rgA = row0 + lane16;
    int bA  = rgA >= Nn;
    int nA  = rgA - bA * Nn;
    const unsigned short* Arow = Abf + (size_t)nA * 256 + bA * 128;
    frag16 a[4];
    #pragma unroll
    for (int q = 0; q < 4; ++q) {
        int k0 = q * 32 + row_q * 8;
        a[q] = *(const frag16*)(Arow + k0);
    }

    f32x4 acc[8];
    #pragma unroll
    for (int c = 0; c < 8; ++c) {
        int n = c * 16 + lane16;
        float d = dpart[0][n] + dpart[1][n];
        acc[c] = (f32x4){d, d, d, d};
    }

    #pragma unroll
    for (int c = 0; c < 8; ++c) {
        int n = c * 16 + lane16;
        #pragma unroll
        for (int q = 0; q < 4; ++q) {
            int k0 = q * 32 + row_q * 8;
            frag16 b = *(const frag16*)&Wl[n * 136 + k0];
            acc[c] = __builtin_amdgcn_mfma_f32_16x16x32_bf16(a[q], b, acc[c], 0, 0, 0);
        }
    }

    #pragma unroll
    for (int r = 0; r < 4; ++r) {
        int rg = row0 + row_q * 4 + r;
        int b  = rg >= Nn;
        int n  = rg - b * Nn;
        float dv = dinv[n];
        unsigned short* dst = Hout + (size_t)n * 256 + b * 128;
        #pragma unroll
        for (int c = 0; c < 8; ++c)
            dst[c * 16 + lane16] = (unsigned short)bf(acc[c][r] * dv);
    }
}

// ---------------- Aggregation: pure-sum gather, 1 wave = 1 node, 2 edges/instr ----------------
// Lane l: edge j+(l>>5), uint4 chunk g=l&31 of the 512B row (batch g>>4, cols (g&15)*8..+7).
// 16B/lane loads, 16 edges in flight at unroll-8; half-wave partials combined by shfl_xor(32).
__device__ inline void acc8(const uint4& v, float& a0, float& a1, float& a2, float& a3,
                            float& a4, float& a5, float& a6, float& a7) {
    a0 += lo16(v.x); a1 += hi16(v.x);
    a2 += lo16(v.y); a3 += hi16(v.y);
    a4 += lo16(v.z); a5 += hi16(v.z);
    a6 += lo16(v.w); a7 += hi16(v.w);
}

__global__ __launch_bounds__(256) void agg_k(const unsigned short* __restrict__ h,
                                             const int* __restrict__ ell,
                                             const int* __restrict__ cnt,
                                             const float* __restrict__ dinv,
                                             const float* __restrict__ bias,
                                             unsigned short* __restrict__ act,
                                             float* __restrict__ S) {
    int t  = threadIdx.x;
    int wv = t >> 6;
    int l  = t & 63;
    int n  = __builtin_amdgcn_readfirstlane(blockIdx.x * 4 + wv);  // wave-uniform -> SGPR
    int half = l >> 5;
    int g    = l & 31;

    const uint4* h4 = (const uint4*)h;   // row n = h4[n*32 .. n*32+31]

    float a0 = 0.f, a1 = 0.f, a2 = 0.f, a3 = 0.f, a4 = 0.f, a5 = 0.f, a6 = 0.f, a7 = 0.f;

    int deg = cnt[n]; if (deg > ELLW) deg = ELLW;
    const int* row = ell + (size_t)n * ELLW;

    int j = 0;
    for (; j + 15 < deg; j += 16) {
        int i0 = row[j +  0 + half], i1 = row[j +  2 + half];
        int i2 = row[j +  4 + half], i3 = row[j +  6 + half];
        int i4 = row[j +  8 + half], i5 = row[j + 10 + half];
        int i6 = row[j + 12 + half], i7 = row[j + 14 + half];
        uint4 v0 = h4[(size_t)i0 * 32 + g];
        uint4 v1 = h4[(size_t)i1 * 32 + g];
        uint4 v2 = h4[(size_t)i2 * 32 + g];
        uint4 v3 = h4[(size_t)i3 * 32 + g];
        uint4 v4 = h4[(size_t)i4 * 32 + g];
        uint4 v5 = h4[(size_t)i5 * 32 + g];
        uint4 v6 = h4[(size_t)i6 * 32 + g];
        uint4 v7 = h4[(size_t)i7 * 32 + g];
        acc8(v0, a0, a1, a2, a3, a4, a5, a6, a7);
        acc8(v1, a0, a1, a2, a3, a4, a5, a6, a7);
        acc8(v2, a0, a1, a2, a3, a4, a5, a6, a7);
        acc8(v3, a0, a1, a2, a3, a4, a5, a6, a7);
        acc8(v4, a0, a1, a2, a3, a4, a5, a6, a7);
        acc8(v5, a0, a1, a2, a3, a4, a5, a6, a7);
        acc8(v6, a0, a1, a2, a3, a4, a5, a6, a7);
        acc8(v7, a0, a1, a2, a3, a4, a5, a6, a7);
    }
    for (; j + 3 < deg; j += 4) {
        int i0 = row[j + half];
        int i1 = row[j + 2 + half];
        uint4 v0 = h4[(size_t)i0 * 32 + g];
        uint4 v1 = h4[(size_t)i1 * 32 + g];
        acc8(v0, a0, a1, a2, a3, a4, a5, a6, a7);
        acc8(v1, a0, a1, a2, a3, a4, a5, a6, a7);
    }
    for (; j + 1 < deg; j += 2) {
        int i0 = row[j + half];
        uint4 v0 = h4[(size_t)i0 * 32 + g];
        acc8(v0, a0, a1, a2, a3, a4, a5, a6, a7);
    }
    if (j < deg) {               // odd last edge: half-0 lanes only
        if (half == 0) {
            int i0 = row[j];
            uint4 v0 = h4[(size_t)i0 * 32 + g];
            acc8(v0, a0, a1, a2, a3, a4, a5, a6, a7);
        }
    }

    // combine half-wave partials (symmetric: every lane gets the total)
    a0 += __shfl_xor(a0, 32); a1 += __shfl_xor(a1, 32);
    a2 += __shfl_xor(a2, 32); a3 += __shfl_xor(a3, 32);
    a4 += __shfl_xor(a4, 32); a5 += __shfl_xor(a5, 32);
    a6 += __shfl_xor(a6, 32); a7 += __shfl_xor(a7, 32);

    // self-loop + scale + bias + ReLU (h already dinv-scaled)
    float dn = dinv[n];
    uint4 u  = h4[(size_t)n * 32 + g];
    int cb   = (g & 15) * 8;
    float4 b0 = *(const float4*)(bias + cb);
    float4 b1 = *(const float4*)(bias + cb + 4);
    float o0 = fmaxf(fmaf(dn, a0 + lo16(u.x), b0.x), 0.f);
    float o1 = fmaxf(fmaf(dn, a1 + hi16(u.x), b0.y), 0.f);
    float o2 = fmaxf(fmaf(dn, a2 + lo16(u.y), b0.z), 0.f);
    float o3 = fmaxf(fmaf(dn, a3 + hi16(u.y), b0.w), 0.f);
    float o4 = fmaxf(fmaf(dn, a4 + lo16(u.z), b1.x), 0.f);
    float o5 = fmaxf(fmaf(dn, a5 + hi16(u.z), b1.y), 0.f);
    float o6 = fmaxf(fmaf(dn, a6 + lo16(u.w), b1.z), 0.f);
    float o7 = fmaxf(fmaf(dn, a7 + hi16(u.w), b1.w), 0.f);

    if (l < 32) {
        uint4 st;
        st.x = pack2(o0, o1); st.y = pack2(o2, o3);
        st.z = pack2(o4, o5); st.w = pack2(o6, o7);
        *(uint4*)(act + (size_t)n * 256 + (size_t)g * 8) = st;
    }

    // ---- fused BN stats: batch-pair reduce (lanes g and g^16 hold same cols) ----
    float q0 = o0 * o0, q1 = o1 * o1, q2 = o2 * o2, q3 = o3 * o3;
    float q4 = o4 * o4, q5 = o5 * o5, q6 = o6 * o6, q7 = o7 * o7;
    float s0 = o0 + __shfl_xor(o0, 16), s1 = o1 + __shfl_xor(o1, 16);
    float s2 = o2 + __shfl_xor(o2, 16), s3 = o3 + __shfl_xor(o3, 16);
    float s4 = o4 + __shfl_xor(o4, 16), s5 = o5 + __shfl_xor(o5, 16);
    float s6 = o6 + __shfl_xor(o6, 16), s7 = o7 + __shfl_xor(o7, 16);
    float t0 = q0 + __shfl_xor(q0, 16), t1 = q1 + __shfl_xor(q1, 16);
    float t2 = q2 + __shfl_xor(q2, 16), t3 = q3 + __shfl_xor(q3, 16);
    float t4 = q4 + __shfl_xor(q4, 16), t5 = q5 + __shfl_xor(q5, 16);
    float t6 = q6 + __shfl_xor(q6, 16), t7 = q7 + __shfl_xor(q7, 16);

    __shared__ float sh[4][16][17];  // [wave][g<16][8 sum + 8 sumsq], pad 17
    if (l < 16) {
        float* p = sh[wv][l];
        p[0] = s0; p[1] = s1; p[2] = s2; p[3] = s3;
        p[4] = s4; p[5] = s5; p[6] = s6; p[7] = s7;
        p[8]  = t0; p[9]  = t1; p[10] = t2; p[11] = t3;
        p[12] = t4; p[13] = t5; p[14] = t6; p[15] = t7;
    }
    __syncthreads();
    int col  = t & 127, stat = t >> 7;
    int gi   = col >> 3, slot = (col & 7) + stat * 8;
    float v = sh[0][gi][slot] + sh[1][gi][slot] + sh[2][gi][slot] + sh[3][gi][slot];
    atomicAdd(&S[stat * 128 + col], v);
}

// ---------------- classifier: (bf16 act, BN2 affine computed in-block) @ Wc + bc ----------------
__global__ __launch_bounds__(256) void gemmout_k(const unsigned short* __restrict__ act,
                                                 const float* __restrict__ Wc,
                                                 const float* __restrict__ bc,
                                                 const float* __restrict__ g,
                                                 const float* __restrict__ bt,
                                                 const float* __restrict__ S,
                                                 float* __restrict__ out) {
    __shared__ float Wl[128 * OUTd];
    __shared__ float bl[OUTd];
    __shared__ float al[128], cl[128];
    int t = threadIdx.x;
    for (int i = t; i < 128 * OUTd; i += 256) Wl[i] = Wc[i];
    if (t < OUTd) bl[t] = bc[t];
    if (t < 128) {
        float s  = S[t];
        float ss = S[128 + t];
        float m   = s * INV_M;
        float var = ss * INV_M - m * m;
        float a   = g[t] * rsqrtf(var + EPSV);
        al[t] = a;
        cl[t] = bt[t] - m * a;
    }
    __syncthreads();

    int r = blockIdx.x * 256 + t;
    if (r >= Mm) return;
    int b = r >= Nn;
    int n = r - b * Nn;

    float acc[OUTd];
    #pragma unroll
    for (int jj = 0; jj < OUTd; jj++) acc[jj] = 0.f;

    const uint4* a4 = (const uint4*)(act + (size_t)n * 256 + b * 128);
    #pragma unroll 4
    for (int k4 = 0; k4 < 16; k4++) {
        uint4 u = a4[k4];
        int k = k4 * 8;
        float e0 = lo16(u.x) * al[k+0] + cl[k+0];
        float e1 = hi16(u.x) * al[k+1] + cl[k+1];
        float e2 = lo16(u.y) * al[k+2] + cl[k+2];
        float e3 = hi16(u.y) * al[k+3] + cl[k+3];
        float e4 = lo16(u.z) * al[k+4] + cl[k+4];
        float e5 = hi16(u.z) * al[k+5] + cl[k+5];
        float e6 = lo16(u.w) * al[k+6] + cl[k+6];
        float e7 = hi16(u.w) * al[k+7] + cl[k+7];
        #pragma unroll
        for (int jj = 0; jj < OUTd; jj++) {
            acc[jj] += e0 * Wl[(k+0) * OUTd + jj];
            acc[jj] += e1 * Wl[(k+1) * OUTd + jj];
            acc[jj] += e2 * Wl[(k+2) * OUTd + jj];
            acc[jj] += e3 * Wl[(k+3) * OUTd + jj];
            acc[jj] += e4 * Wl[(k+4) * OUTd + jj];
            acc[jj] += e5 * Wl[(k+5) * OUTd + jj];
            acc[jj] += e6 * Wl[(k+6) * OUTd + jj];
            acc[jj] += e7 * Wl[(k+7) * OUTd + jj];
        }
    }
    #pragma unroll
    for (int jj = 0; jj < OUTd; jj++) out[(size_t)r * OUTd + jj] = acc[jj] + bl[jj];
}

extern "C" void kernel_launch(void* const* d_in, const int* in_sizes, int n_in,
                              void* d_out, int out_size, void* d_ws, size_t ws_size,
                              hipStream_t stream) {
    (void)in_sizes; (void)n_in; (void)out_size; (void)ws_size;

    const float* x   = (const float*)d_in[0];
    const float* W1  = (const float*)d_in[1];
    const float* b1  = (const float*)d_in[2];
    const float* W2  = (const float*)d_in[3];
    const float* b2  = (const float*)d_in[4];
    const float* g1  = (const float*)d_in[5];
    const float* bt1 = (const float*)d_in[6];
    const float* g2  = (const float*)d_in[7];
    const float* bt2 = (const float*)d_in[8];
    const float* Wc  = (const float*)d_in[9];
    const float* bc  = (const float*)d_in[10];
    const int*   ei  = (const int*)d_in[11];
    const int* srcp = ei;        // edge_index[0]
    const int* dstp = ei + Ee;   // edge_index[1]

    char* ws = (char*)d_ws;
    size_t off = 0;
    auto alloc = [&](size_t bytes) -> void* {
        void* p = ws + off;
        off += (bytes + 511) & ~(size_t)511;
        return p;
    };
    unsigned short* h   = (unsigned short*)alloc((size_t)Mm * 128 * 2);  // bf16 interleaved, dinv-scaled
    unsigned short* act = (unsigned short*)alloc((size_t)Mm * 128 * 2);  // bf16 interleaved
    float* dinv = (float*)alloc(Nn * 4);
    int*   cnt  = (int*)alloc(Nn * 4 + 2 * 256 * 4);  // cnt + S1 + S2 contiguous (one memset)
    float* S1   = (float*)(cnt + Nn);                 // sum[128], sumsq[128]
    float* S2   = S1 + 256;
    int*   ell  = (int*)alloc((size_t)Nn * ELLW * 4);

    float* out = (float*)d_out;

    // adjacency + stat-accumulator zeroing (1 memset + 2 kernels)
    hipMemsetAsync(cnt, 0, Nn * 4 + 2 * 256 * 4, stream);
    scatter_ell_k<<<(Ee + 255) / 256, 256, 0, stream>>>(srcp, dstp, cnt, ell);
    dinv_k<<<(Nn + 255) / 256, 256, 0, stream>>>(cnt, dinv);

    // Layer 1
    gemm1_k<<<Mm / 64, 256, 0, stream>>>(x, W1, dinv, h);
    agg_k<<<Nn / 4, 256, 0, stream>>>(h, ell, cnt, dinv, b1, act, S1);

    // Layer 2 (BN1 affine + d-init computed per-block inside gemm2)
    gemm2_k<<<Mm / 64, 256, 0, stream>>>(act, W2, g1, bt1, S1, dinv, h);
    agg_k<<<Nn / 4, 256, 0, stream>>>(h, ell, cnt, dinv, b2, act, S2);

    // Classifier (BN2 affine computed per-block)
    gemmout_k<<<(Mm + 255) / 256, 256, 0, stream>>>(act, Wc, bc, g2, bt2, S2, out);
}

// Round 3
// 244.600 us; speedup vs baseline: 1.7494x; 1.7494x over previous
//
#include <hip/hip_runtime.h>
#include <hip/hip_bf16.h>

// GCN: 2x (GCNConv -> ReLU -> BatchNorm) -> Linear
// B=2, N=20000, E=640000, H=IN=128, OUT=10
//
// Round-6 structure (8 dispatches):
//  - ELL adjacency in ONE scatter pass (atomic cursor == degree counter)
//  - h pre-scaled by dinv at GEMM epilogue: agg is a pure unweighted sum
//  - agg: 1 wave = 1 node, 2 edges per uint4 load instruction
//  - BN stats FUSED into agg epilogue; SLOTTED accumulator S[64][256]
//    (slot = blockIdx&63) to break atomic same-line contention
//    (round-5 bug: 1.28M atomics into 256 addrs serialized ~85us/agg)
//  - consumers (gemm2/gemmout) reduce the 64 slots in their prologue
//  - BN affine computed per-block in consumers; no finalize dispatches

constexpr int Nn   = 20000;
constexpr int Ee   = 640000;
constexpr int OUTd = 10;
constexpr int Mm   = 2 * Nn;   // 40000 rows
constexpr int ELLW = 96;       // max degree slots; Poisson(32) => P(overflow) ~ 1e-14
constexpr int NSLOT = 64;      // stat accumulator slots (contention spreading)
#define EPSV 1e-5f
constexpr float INV_M = 1.0f / (float)Mm;

using frag16 = __attribute__((ext_vector_type(8))) short;  // 8 bf16
using f32x4  = __attribute__((ext_vector_type(4))) float;

__device__ inline short bf(float f) {
    union { __hip_bfloat16 h; short s; } u;
    u.h = __float2bfloat16(f);
    return u.s;
}
__device__ inline float lo16(unsigned u) { union { unsigned v; float f; } x; x.v = u << 16;        return x.f; }
__device__ inline float hi16(unsigned u) { union { unsigned v; float f; } x; x.v = u & 0xffff0000u; return x.f; }
__device__ inline unsigned pack2(float f0, float f1) {
    return (unsigned)(unsigned short)bf(f0) | ((unsigned)(unsigned short)bf(f1) << 16);
}

// ---------------- adjacency: one-pass ELL scatter ----------------
__global__ __launch_bounds__(256) void scatter_ell_k(const int* __restrict__ src, const int* __restrict__ dst,
                                                     int* __restrict__ cnt, int* __restrict__ ell) {
    int e = blockIdx.x * 256 + threadIdx.x;
    if (e < Ee) {
        int d = dst[e];
        int pos = atomicAdd(&cnt[d], 1);
        if (pos < ELLW) ell[(size_t)d * ELLW + pos] = src[e];
    }
}

__global__ __launch_bounds__(256) void dinv_k(const int* __restrict__ cnt, float* __restrict__ dinv) {
    int n = blockIdx.x * 256 + threadIdx.x;
    if (n < Nn) dinv[n] = rsqrtf((float)cnt[n] + 1.0f);  // +1 self-loop
}

// ---------------- GEMM1: (40000 x 128 fp32) @ (128 x 128) -> dinv-scaled bf16 interleaved ----------------
__global__ __launch_bounds__(256) void gemm1_k(const float* __restrict__ A,
                                               const float* __restrict__ W,
                                               const float* __restrict__ dinv,
                                               unsigned short* __restrict__ Hout) {
    __shared__ short Wl[128 * 136];  // Wl[n*136 + k] bf16; stride 272B -> free 2-way
    int t = threadIdx.x;

    for (int it = 0; it < 8; ++it) {
        int lin = it * 256 + t;
        int kp  = lin & 63;
        int n4  = (lin >> 6) * 4;
        float4 w0 = *(const float4*)(W + (size_t)(2 * kp) * 128 + n4);
        float4 w1 = *(const float4*)(W + (size_t)(2 * kp + 1) * 128 + n4);
        *(unsigned*)&Wl[(n4 + 0) * 136 + 2 * kp] = pack2(w0.x, w1.x);
        *(unsigned*)&Wl[(n4 + 1) * 136 + 2 * kp] = pack2(w0.y, w1.y);
        *(unsigned*)&Wl[(n4 + 2) * 136 + 2 * kp] = pack2(w0.z, w1.z);
        *(unsigned*)&Wl[(n4 + 3) * 136 + 2 * kp] = pack2(w0.w, w1.w);
    }
    __syncthreads();

    int wv = t >> 6, l = t & 63;
    int row_q = l >> 4, lane16 = l & 15;
    int row0 = blockIdx.x * 64 + wv * 16;

    frag16 a[4];
    const float* Arow = A + (size_t)(row0 + lane16) * 128;
    #pragma unroll
    for (int q = 0; q < 4; ++q) {
        int k0 = q * 32 + row_q * 8;
        float4 v0 = *(const float4*)(Arow + k0);
        float4 v1 = *(const float4*)(Arow + k0 + 4);
        frag16 fa = { bf(v0.x), bf(v0.y), bf(v0.z), bf(v0.w),
                      bf(v1.x), bf(v1.y), bf(v1.z), bf(v1.w) };
        a[q] = fa;
    }

    f32x4 acc[8];
    #pragma unroll
    for (int c = 0; c < 8; ++c) acc[c] = (f32x4){0.f, 0.f, 0.f, 0.f};

    #pragma unroll
    for (int c = 0; c < 8; ++c) {
        int n = c * 16 + lane16;
        #pragma unroll
        for (int q = 0; q < 4; ++q) {
            int k0 = q * 32 + row_q * 8;
            frag16 b = *(const frag16*)&Wl[n * 136 + k0];
            acc[c] = __builtin_amdgcn_mfma_f32_16x16x32_bf16(a[q], b, acc[c], 0, 0, 0);
        }
    }

    #pragma unroll
    for (int r = 0; r < 4; ++r) {
        int rg = row0 + row_q * 4 + r;
        int b  = rg >= Nn;
        int n  = rg - b * Nn;
        float dv = dinv[n];
        unsigned short* dst = Hout + (size_t)n * 256 + b * 128;
        #pragma unroll
        for (int c = 0; c < 8; ++c)
            dst[c * 16 + lane16] = (unsigned short)bf(acc[c][r] * dv);
    }
}

// ---------------- GEMM2: (bf16 act) @ (diag(a1)*W2) + c1@W2 -> dinv-scaled bf16 ----------------
__global__ __launch_bounds__(256) void gemm2_k(const unsigned short* __restrict__ Abf,
                                               const float* __restrict__ W,
                                               const float* __restrict__ g,
                                               const float* __restrict__ bt,
                                               const float* __restrict__ S,
                                               const float* __restrict__ dinv,
                                               unsigned short* __restrict__ Hout) {
    __shared__ short Wl[128 * 136];
    __shared__ float al[128], cl[128], dpart[2][128];
    int t = threadIdx.x;

    if (t < 128) {
        float s = 0.f, ss = 0.f;
        #pragma unroll 8
        for (int k = 0; k < NSLOT; ++k) {
            s  += S[k * 256 + t];
            ss += S[k * 256 + 128 + t];
        }
        float m   = s * INV_M;
        float var = ss * INV_M - m * m;
        float a   = g[t] * rsqrtf(var + EPSV);
        float c   = bt[t] - m * a;
        al[t] = a; cl[t] = c;
    }
    __syncthreads();

    // stage W scaled by a (rows k scaled by a[k])
    for (int it = 0; it < 8; ++it) {
        int lin = it * 256 + t;
        int kp  = lin & 63;
        int n4  = (lin >> 6) * 4;
        float a0 = al[2 * kp], a1 = al[2 * kp + 1];
        float4 w0 = *(const float4*)(W + (size_t)(2 * kp) * 128 + n4);
        float4 w1 = *(const float4*)(W + (size_t)(2 * kp + 1) * 128 + n4);
        w0.x *= a0; w0.y *= a0; w0.z *= a0; w0.w *= a0;
        w1.x *= a1; w1.y *= a1; w1.z *= a1; w1.w *= a1;
        *(unsigned*)&Wl[(n4 + 0) * 136 + 2 * kp] = pack2(w0.x, w1.x);
        *(unsigned*)&Wl[(n4 + 1) * 136 + 2 * kp] = pack2(w0.y, w1.y);
        *(unsigned*)&Wl[(n4 + 2) * 136 + 2 * kp] = pack2(w0.z, w1.z);
        *(unsigned*)&Wl[(n4 + 3) * 136 + 2 * kp] = pack2(w0.w, w1.w);
    }

    // d[col] = sum_k c[k] * W[k][col], split over two half-K per thread
    {
        int col = t & 127, hh = t >> 7;
        const float* Wc0 = W + (size_t)(hh * 64) * 128 + col;
        float dp = 0.f;
        #pragma unroll 8
        for (int k = 0; k < 64; ++k) dp += cl[hh * 64 + k] * Wc0[(size_t)k * 128];
        dpart[hh][col] = dp;
    }
    __syncthreads();

    int wv = t >> 6, l = t & 63;
    int row_q = l >> 4, lane16 = l & 15;
    int row0 = blockIdx.x * 64 + wv * 16;

    int rgA = row0 + lane16;
    int bA  = rgA >= Nn;
    int nA  = rgA - bA * Nn;
    const unsigned short* Arow = Abf + (size_t)nA * 256 + bA * 128;
    frag16 a[4];
    #pragma unroll
    for (int q = 0; q < 4; ++q) {
        int k0 = q * 32 + row_q * 8;
        a[q] = *(const frag16*)(Arow + k0);
    }

    f32x4 acc[8];
    #pragma unroll
    for (int c = 0; c < 8; ++c) {
        int n = c * 16 + lane16;
        float d = dpart[0][n] + dpart[1][n];
        acc[c] = (f32x4){d, d, d, d};
    }

    #pragma unroll
    for (int c = 0; c < 8; ++c) {
        int n = c * 16 + lane16;
        #pragma unroll
        for (int q = 0; q < 4; ++q) {
            int k0 = q * 32 + row_q * 8;
            frag16 b = *(const frag16*)&Wl[n * 136 + k0];
            acc[c] = __builtin_amdgcn_mfma_f32_16x16x32_bf16(a[q], b, acc[c], 0, 0, 0);
        }
    }

    #pragma unroll
    for (int r = 0; r < 4; ++r) {
        int rg = row0 + row_q * 4 + r;
        int b  = rg >= Nn;
        int n  = rg - b * Nn;
        float dv = dinv[n];
        unsigned short* dst = Hout + (size_t)n * 256 + b * 128;
        #pragma unroll
        for (int c = 0; c < 8; ++c)
            dst[c * 16 + lane16] = (unsigned short)bf(acc[c][r] * dv);
    }
}

// ---------------- Aggregation: pure-sum gather, 1 wave = 1 node, 2 edges/instr ----------------
// Lane l: edge j+(l>>5), uint4 chunk g=l&31 of the 512B row (batch g>>4, cols (g&15)*8..+7).
__device__ inline void acc8(const uint4& v, float& a0, float& a1, float& a2, float& a3,
                            float& a4, float& a5, float& a6, float& a7) {
    a0 += lo16(v.x); a1 += hi16(v.x);
    a2 += lo16(v.y); a3 += hi16(v.y);
    a4 += lo16(v.z); a5 += hi16(v.z);
    a6 += lo16(v.w); a7 += hi16(v.w);
}

__global__ __launch_bounds__(256) void agg_k(const unsigned short* __restrict__ h,
                                             const int* __restrict__ ell,
                                             const int* __restrict__ cnt,
                                             const float* __restrict__ dinv,
                                             const float* __restrict__ bias,
                                             unsigned short* __restrict__ act,
                                             float* __restrict__ S) {
    int t  = threadIdx.x;
    int wv = t >> 6;
    int l  = t & 63;
    int n  = __builtin_amdgcn_readfirstlane(blockIdx.x * 4 + wv);  // wave-uniform -> SGPR
    int half = l >> 5;
    int g    = l & 31;

    const uint4* h4 = (const uint4*)h;   // row n = h4[n*32 .. n*32+31]

    float a0 = 0.f, a1 = 0.f, a2 = 0.f, a3 = 0.f, a4 = 0.f, a5 = 0.f, a6 = 0.f, a7 = 0.f;

    int deg = cnt[n]; if (deg > ELLW) deg = ELLW;
    const int* row = ell + (size_t)n * ELLW;

    int j = 0;
    for (; j + 15 < deg; j += 16) {
        int i0 = row[j +  0 + half], i1 = row[j +  2 + half];
        int i2 = row[j +  4 + half], i3 = row[j +  6 + half];
        int i4 = row[j +  8 + half], i5 = row[j + 10 + half];
        int i6 = row[j + 12 + half], i7 = row[j + 14 + half];
        uint4 v0 = h4[(size_t)i0 * 32 + g];
        uint4 v1 = h4[(size_t)i1 * 32 + g];
        uint4 v2 = h4[(size_t)i2 * 32 + g];
        uint4 v3 = h4[(size_t)i3 * 32 + g];
        uint4 v4 = h4[(size_t)i4 * 32 + g];
        uint4 v5 = h4[(size_t)i5 * 32 + g];
        uint4 v6 = h4[(size_t)i6 * 32 + g];
        uint4 v7 = h4[(size_t)i7 * 32 + g];
        acc8(v0, a0, a1, a2, a3, a4, a5, a6, a7);
        acc8(v1, a0, a1, a2, a3, a4, a5, a6, a7);
        acc8(v2, a0, a1, a2, a3, a4, a5, a6, a7);
        acc8(v3, a0, a1, a2, a3, a4, a5, a6, a7);
        acc8(v4, a0, a1, a2, a3, a4, a5, a6, a7);
        acc8(v5, a0, a1, a2, a3, a4, a5, a6, a7);
        acc8(v6, a0, a1, a2, a3, a4, a5, a6, a7);
        acc8(v7, a0, a1, a2, a3, a4, a5, a6, a7);
    }
    for (; j + 3 < deg; j += 4) {
        int i0 = row[j + half];
        int i1 = row[j + 2 + half];
        uint4 v0 = h4[(size_t)i0 * 32 + g];
        uint4 v1 = h4[(size_t)i1 * 32 + g];
        acc8(v0, a0, a1, a2, a3, a4, a5, a6, a7);
        acc8(v1, a0, a1, a2, a3, a4, a5, a6, a7);
    }
    for (; j + 1 < deg; j += 2) {
        int i0 = row[j + half];
        uint4 v0 = h4[(size_t)i0 * 32 + g];
        acc8(v0, a0, a1, a2, a3, a4, a5, a6, a7);
    }
    if (j < deg) {               // odd last edge: half-0 lanes only
        if (half == 0) {
            int i0 = row[j];
            uint4 v0 = h4[(size_t)i0 * 32 + g];
            acc8(v0, a0, a1, a2, a3, a4, a5, a6, a7);
        }
    }

    // combine half-wave partials (symmetric: every lane gets the total)
    a0 += __shfl_xor(a0, 32); a1 += __shfl_xor(a1, 32);
    a2 += __shfl_xor(a2, 32); a3 += __shfl_xor(a3, 32);
    a4 += __shfl_xor(a4, 32); a5 += __shfl_xor(a5, 32);
    a6 += __shfl_xor(a6, 32); a7 += __shfl_xor(a7, 32);

    // self-loop + scale + bias + ReLU (h already dinv-scaled)
    float dn = dinv[n];
    uint4 u  = h4[(size_t)n * 32 + g];
    int cb   = (g & 15) * 8;
    float4 b0 = *(const float4*)(bias + cb);
    float4 b1 = *(const float4*)(bias + cb + 4);
    float o0 = fmaxf(fmaf(dn, a0 + lo16(u.x), b0.x), 0.f);
    float o1 = fmaxf(fmaf(dn, a1 + hi16(u.x), b0.y), 0.f);
    float o2 = fmaxf(fmaf(dn, a2 + lo16(u.y), b0.z), 0.f);
    float o3 = fmaxf(fmaf(dn, a3 + hi16(u.y), b0.w), 0.f);
    float o4 = fmaxf(fmaf(dn, a4 + lo16(u.z), b1.x), 0.f);
    float o5 = fmaxf(fmaf(dn, a5 + hi16(u.z), b1.y), 0.f);
    float o6 = fmaxf(fmaf(dn, a6 + lo16(u.w), b1.z), 0.f);
    float o7 = fmaxf(fmaf(dn, a7 + hi16(u.w), b1.w), 0.f);

    if (l < 32) {
        uint4 st;
        st.x = pack2(o0, o1); st.y = pack2(o2, o3);
        st.z = pack2(o4, o5); st.w = pack2(o6, o7);
        *(uint4*)(act + (size_t)n * 256 + (size_t)g * 8) = st;
    }

    // ---- fused BN stats: batch-pair reduce (lanes g and g^16 hold same cols) ----
    float q0 = o0 * o0, q1 = o1 * o1, q2 = o2 * o2, q3 = o3 * o3;
    float q4 = o4 * o4, q5 = o5 * o5, q6 = o6 * o6, q7 = o7 * o7;
    float s0 = o0 + __shfl_xor(o0, 16), s1 = o1 + __shfl_xor(o1, 16);
    float s2 = o2 + __shfl_xor(o2, 16), s3 = o3 + __shfl_xor(o3, 16);
    float s4 = o4 + __shfl_xor(o4, 16), s5 = o5 + __shfl_xor(o5, 16);
    float s6 = o6 + __shfl_xor(o6, 16), s7 = o7 + __shfl_xor(o7, 16);
    float t0 = q0 + __shfl_xor(q0, 16), t1 = q1 + __shfl_xor(q1, 16);
    float t2 = q2 + __shfl_xor(q2, 16), t3 = q3 + __shfl_xor(q3, 16);
    float t4 = q4 + __shfl_xor(q4, 16), t5 = q5 + __shfl_xor(q5, 16);
    float t6 = q6 + __shfl_xor(q6, 16), t7 = q7 + __shfl_xor(q7, 16);

    __shared__ float sh[4][16][17];  // [wave][g<16][8 sum + 8 sumsq], pad 17
    if (l < 16) {
        float* p = sh[wv][l];
        p[0] = s0; p[1] = s1; p[2] = s2; p[3] = s3;
        p[4] = s4; p[5] = s5; p[6] = s6; p[7] = s7;
        p[8]  = t0; p[9]  = t1; p[10] = t2; p[11] = t3;
        p[12] = t4; p[13] = t5; p[14] = t6; p[15] = t7;
    }
    __syncthreads();
    int col  = t & 127, stat = t >> 7;
    int gi   = col >> 3, slot = (col & 7) + stat * 8;
    float v = sh[0][gi][slot] + sh[1][gi][slot] + sh[2][gi][slot] + sh[3][gi][slot];
    // slotted accumulator: spread contention across 64 copies (64KB span)
    atomicAdd(&S[(blockIdx.x & (NSLOT - 1)) * 256 + stat * 128 + col], v);
}

// ---------------- classifier: (bf16 act, BN2 affine computed in-block) @ Wc + bc ----------------
__global__ __launch_bounds__(256) void gemmout_k(const unsigned short* __restrict__ act,
                                                 const float* __restrict__ Wc,
                                                 const float* __restrict__ bc,
                                                 const float* __restrict__ g,
                                                 const float* __restrict__ bt,
                                                 const float* __restrict__ S,
                                                 float* __restrict__ out) {
    __shared__ float Wl[128 * OUTd];
    __shared__ float bl[OUTd];
    __shared__ float al[128], cl[128];
    int t = threadIdx.x;
    for (int i = t; i < 128 * OUTd; i += 256) Wl[i] = Wc[i];
    if (t < OUTd) bl[t] = bc[t];
    if (t < 128) {
        float s = 0.f, ss = 0.f;
        #pragma unroll 8
        for (int k = 0; k < NSLOT; ++k) {
            s  += S[k * 256 + t];
            ss += S[k * 256 + 128 + t];
        }
        float m   = s * INV_M;
        float var = ss * INV_M - m * m;
        float a   = g[t] * rsqrtf(var + EPSV);
        al[t] = a;
        cl[t] = bt[t] - m * a;
    }
    __syncthreads();

    int r = blockIdx.x * 256 + t;
    if (r >= Mm) return;
    int b = r >= Nn;
    int n = r - b * Nn;

    float acc[OUTd];
    #pragma unroll
    for (int jj = 0; jj < OUTd; jj++) acc[jj] = 0.f;

    const uint4* a4 = (const uint4*)(act + (size_t)n * 256 + b * 128);
    #pragma unroll 4
    for (int k4 = 0; k4 < 16; k4++) {
        uint4 u = a4[k4];
        int k = k4 * 8;
        float e0 = lo16(u.x) * al[k+0] + cl[k+0];
        float e1 = hi16(u.x) * al[k+1] + cl[k+1];
        float e2 = lo16(u.y) * al[k+2] + cl[k+2];
        float e3 = hi16(u.y) * al[k+3] + cl[k+3];
        float e4 = lo16(u.z) * al[k+4] + cl[k+4];
        float e5 = hi16(u.z) * al[k+5] + cl[k+5];
        float e6 = lo16(u.w) * al[k+6] + cl[k+6];
        float e7 = hi16(u.w) * al[k+7] + cl[k+7];
        #pragma unroll
        for (int jj = 0; jj < OUTd; jj++) {
            acc[jj] += e0 * Wl[(k+0) * OUTd + jj];
            acc[jj] += e1 * Wl[(k+1) * OUTd + jj];
            acc[jj] += e2 * Wl[(k+2) * OUTd + jj];
            acc[jj] += e3 * Wl[(k+3) * OUTd + jj];
            acc[jj] += e4 * Wl[(k+4) * OUTd + jj];
            acc[jj] += e5 * Wl[(k+5) * OUTd + jj];
            acc[jj] += e6 * Wl[(k+6) * OUTd + jj];
            acc[jj] += e7 * Wl[(k+7) * OUTd + jj];
        }
    }
    #pragma unroll
    for (int jj = 0; jj < OUTd; jj++) out[(size_t)r * OUTd + jj] = acc[jj] + bl[jj];
}

extern "C" void kernel_launch(void* const* d_in, const int* in_sizes, int n_in,
                              void* d_out, int out_size, void* d_ws, size_t ws_size,
                              hipStream_t stream) {
    (void)in_sizes; (void)n_in; (void)out_size; (void)ws_size;

    const float* x   = (const float*)d_in[0];
    const float* W1  = (const float*)d_in[1];
    const float* b1  = (const float*)d_in[2];
    const float* W2  = (const float*)d_in[3];
    const float* b2  = (const float*)d_in[4];
    const float* g1  = (const float*)d_in[5];
    const float* bt1 = (const float*)d_in[6];
    const float* g2  = (const float*)d_in[7];
    const float* bt2 = (const float*)d_in[8];
    const float* Wc  = (const float*)d_in[9];
    const float* bc  = (const float*)d_in[10];
    const int*   ei  = (const int*)d_in[11];
    const int* srcp = ei;        // edge_index[0]
    const int* dstp = ei + Ee;   // edge_index[1]

    char* ws = (char*)d_ws;
    size_t off = 0;
    auto alloc = [&](size_t bytes) -> void* {
        void* p = ws + off;
        off += (bytes + 511) & ~(size_t)511;
        return p;
    };
    unsigned short* h   = (unsigned short*)alloc((size_t)Mm * 128 * 2);  // bf16 interleaved, dinv-scaled
    unsigned short* act = (unsigned short*)alloc((size_t)Mm * 128 * 2);  // bf16 interleaved
    float* dinv = (float*)alloc(Nn * 4);
    // cnt + S1 + S2 contiguous (one memset): S are slotted [NSLOT][256]
    int*   cnt  = (int*)alloc(Nn * 4 + 2 * NSLOT * 256 * 4);
    float* S1   = (float*)(cnt + Nn);
    float* S2   = S1 + NSLOT * 256;
    int*   ell  = (int*)alloc((size_t)Nn * ELLW * 4);

    float* out = (float*)d_out;

    // adjacency + stat-accumulator zeroing (1 memset + 2 kernels)
    hipMemsetAsync(cnt, 0, Nn * 4 + 2 * NSLOT * 256 * 4, stream);
    scatter_ell_k<<<(Ee + 255) / 256, 256, 0, stream>>>(srcp, dstp, cnt, ell);
    dinv_k<<<(Nn + 255) / 256, 256, 0, stream>>>(cnt, dinv);

    // Layer 1
    gemm1_k<<<Mm / 64, 256, 0, stream>>>(x, W1, dinv, h);
    agg_k<<<Nn / 4, 256, 0, stream>>>(h, ell, cnt, dinv, b1, act, S1);

    // Layer 2 (BN1 affine + d-init computed per-block inside gemm2)
    gemm2_k<<<Mm / 64, 256, 0, stream>>>(act, W2, g1, bt1, S1, dinv, h);
    agg_k<<<Nn / 4, 256, 0, stream>>>(h, ell, cnt, dinv, b2, act, S2);

    // Classifier (BN2 affine computed per-block)
    gemmout_k<<<(Mm + 255) / 256, 256, 0, stream>>>(act, Wc, bc, g2, bt2, S2, out);
}